// Round 4
// baseline (119.072 us; speedup 1.0000x reference)
//
#include <hip/hip_runtime.h>
#include <hip/hip_bf16.h>

// MultiHeadCrossAttention: B=2,S=2048,D=1024,H=16,HD=64
// prep(cvt emb + transpose weights, fused),
// merged KV+Q GEMM: 256x256/BK=64, 8 waves, m201-style 8-PHASE counted-vmcnt
// schedule (4 quadrant-phases per K-tile, half-tile-granular staging, vmcnt(6)
// steady state, sched_barrier-pinned barriers),
// swapped-operand flash-attn (round-1 verified structure),
// out GEMM on verified 128^2 kernel.

typedef unsigned short ushort;
typedef __attribute__((ext_vector_type(4))) float f32x4;
typedef __attribute__((ext_vector_type(16))) float f32x16;
typedef __attribute__((ext_vector_type(8))) __bf16 bf16x8;
typedef __attribute__((ext_vector_type(8))) unsigned short u16x8;
typedef __attribute__((ext_vector_type(4))) unsigned short u16x4;
typedef __attribute__((ext_vector_type(4))) unsigned int u32x4;

#define LOG2E 1.44269504088896340736f

constexpr int Bc = 2, Sc = 2048, Dc = 1024, Hc = 16, HDc = 64;

__device__ inline ushort f2bf(float f) {
    unsigned u = __builtin_bit_cast(unsigned, f);
    u += 0x7fffu + ((u >> 16) & 1u);   // RNE (inputs finite)
    return (ushort)(u >> 16);
}

__device__ inline float fexp2(float x) {
#if __has_builtin(__builtin_amdgcn_exp2f)
    return __builtin_amdgcn_exp2f(x);   // single v_exp_f32, hazard-safe
#else
    return exp2f(x);
#endif
}

__device__ inline void gload16(const void* g, void* l) {
    __builtin_amdgcn_global_load_lds((const __attribute__((address_space(1))) void*)g,
                                     (__attribute__((address_space(3))) void*)l, 16, 0, 0);
}

__device__ inline f32x4 mfma16(bf16x8 a, bf16x8 b, f32x4 c) {
    return __builtin_amdgcn_mfma_f32_16x16x32_bf16(a, b, c, 0, 0, 0);
}
__device__ inline f32x16 mfma32(bf16x8 a, bf16x8 b, f32x16 c) {
    return __builtin_amdgcn_mfma_f32_32x32x16_bf16(a, b, c, 0, 0, 0);
}
__device__ inline unsigned cvtpk(float lo, float hi_) {
    unsigned r; asm("v_cvt_pk_bf16_f32 %0, %1, %2" : "=v"(r) : "v"(lo), "v"(hi_)); return r;
}
__device__ inline void swap32(unsigned& a, unsigned& b) {
    asm("v_permlane32_swap_b32 %0, %1" : "+v"(a), "+v"(b));
}

// ---- fused preprocessing: emb cvt (blocks 0..2047) + 3 weight transposes ---
__global__ __launch_bounds__(256) void prep_k(const float* __restrict__ emb,
                                              ushort* __restrict__ embb,
                                              const float* __restrict__ Wkv,
                                              const float* __restrict__ Wq,
                                              const float* __restrict__ Wo,
                                              ushort* __restrict__ WtAll) {
    const int bid = blockIdx.x;
    if (bid < 2048) {                     // emb f32 -> bf16, 8 elems/thread
        int i = bid * 256 + threadIdx.x;
        const float4* p = (const float4*)emb;
        float4 a = p[2 * i], b = p[2 * i + 1];
        u16x8 r;
        r[0] = f2bf(a.x); r[1] = f2bf(a.y); r[2] = f2bf(a.z); r[3] = f2bf(a.w);
        r[4] = f2bf(b.x); r[5] = f2bf(b.y); r[6] = f2bf(b.z); r[7] = f2bf(b.w);
        ((u16x8*)embb)[i] = r;
        return;
    }
    // transpose W (K=1024 x N) -> WtAll rows [rowofs, rowofs+N) x 1024, bf16
    __shared__ float t[32][33];
    int tb = bid - 2048;
    const float* W; int N, rowofs;
    if (tb < 2048)      { W = Wkv; N = 2048; rowofs = 0; }
    else if (tb < 3072) { W = Wq;  N = 1024; rowofs = 2048; tb -= 2048; }
    else                { W = Wo;  N = 1024; rowofs = 3072; tb -= 3072; }
    const int nbx = N >> 5;
    const int bx = tb % nbx, by = tb / nbx;
    const int tx = threadIdx.x & 31, ty = threadIdx.x >> 5;
    const int bj = bx * 32, bi = by * 32;
#pragma unroll
    for (int i = 0; i < 4; i++) {
        int r = ty + i * 8;
        t[r][tx] = W[(size_t)(bi + r) * N + bj + tx];
    }
    __syncthreads();
#pragma unroll
    for (int i = 0; i < 4; i++) {
        int r = ty + i * 8;
        WtAll[(size_t)(rowofs + bj + r) * 1024 + bi + tx] = f2bf(t[tx][r]);
    }
}

// ---- 256x256 / BK=64 KV+Q GEMM, m201-style 8-phase schedule ----------------
// 512 thr = 8 waves (2M wr x 4N wc); per-wave 128x64 out = acc[8][4] f32x4.
// LDS 128KB: sA/sB [2 dbuf][2 half][16KB]. Half-tiles match CONSUMPTION
// quadrants: A-half mh = rows {wr*128 + mh*64 ..+63} for both wr; B-half nh
// = cols {wc*64 + nh*32 ..+31} for all wc.
// Per K-tile, 4 phases compute quadrants (0,0),(0,1),(1,1),(1,0); each phase
// stages ONE half-tile (2 gload16/thread). HT issue order per tile:
// [A0,B1,A1,B0]; stage of a region lands exactly one trailing-barrier after
// that region's last ds_read. vmcnt(6) once per K-tile (3 HT in flight);
// vmcnt(0) only at kt==nk-2. All barriers sched_barrier(0)-pinned.
// Swizzle: LDS slot (row,chunk16) holds global chunk (chunk ^ (row&7));
// staging pre-swizzles the GLOBAL source (linear gload_lds dest, m173);
// fragment reads XOR with (l16&7) -> 2-way conflict (free; r3 measured 0).
__global__ __launch_bounds__(512, 2) void gemm256_kv8_k(const ushort* __restrict__ A,
                                                        const ushort* __restrict__ Bt,
                                                        const float* __restrict__ bias,
                                                        const float* __restrict__ bias2,
                                                        ushort* __restrict__ Kout,
                                                        ushort* __restrict__ Vout,
                                                        ushort* __restrict__ Qout,
                                                        int N, int K) {
    __shared__ __align__(16) char sA[2][32768];   // [mh 16KB: [wr][64r][8chunk]]
    __shared__ __align__(16) char sB[2][32768];   // [nh 16KB: [wc][32c][8chunk]]
    const int tid = threadIdx.x;
    const int nbc = N >> 8;                       // 12
    const int cpx = (gridDim.x >> 3);             // 192 -> 24 (grid%8==0)
    const int swzb = (blockIdx.x & 7) * cpx + (blockIdx.x >> 3);
    const int brow = swzb / nbc, bcol = swzb % nbc;
    const int w = tid >> 6, lane = tid & 63;
    const int wr = w >> 2, wc = w & 3;
    const int lg = lane >> 4, l16 = lane & 15;
    const int lx7 = l16 & 7;

    f32x4 acc[8][4] = {};

    // staging thread map: lane -> (row8 = lane>>3, chunk = lane&7);
    // pre-swizzled global chunk = (lane&7) ^ (lane>>3)   [row&7 == lane>>3]
    const int srow8 = lane >> 3;
    const int sch = (lane & 7) ^ srow8;
    const ushort* Ab = A  + (size_t)(brow * 256 + w * 8 + srow8) * K + sch * 8;
    const ushort* Bb = Bt + (size_t)(bcol * 256 + (w >> 2) * 64 + (w & 3) * 8 + srow8) * K + sch * 8;

    auto ST_A = [&](int buf, int mh, int k0) {    // one 16KB A half-tile
#pragma unroll
        for (int j = 0; j < 2; j++)               // j == dest wr slot
            gload16(Ab + (size_t)(j * 128 + mh * 64) * K + k0,
                    sA[buf] + mh * 16384 + j * 8192 + w * 1024);
    };
    auto ST_B = [&](int buf, int nh, int k0) {    // one 16KB B half-tile
#pragma unroll
        for (int j = 0; j < 2; j++)               // wc slot = j*2 + (w>>2)
            gload16(Bb + (size_t)(j * 128 + nh * 32) * K + k0,
                    sB[buf] + nh * 16384 + j * 8192 + w * 1024);
    };

    bf16x8 af[4][2], bfr[2][2];
    auto LD_A = [&](int buf, int mh) {            // 8 x ds_read_b128
#pragma unroll
        for (int rf = 0; rf < 4; rf++)
#pragma unroll
            for (int ks = 0; ks < 2; ks++)
                af[rf][ks] = *(const bf16x8*)(sA[buf] + mh * 16384 + wr * 8192 +
                             (rf * 16 + l16) * 128 + ((((ks << 2) | lg) ^ lx7) << 4));
    };
    auto LD_B = [&](int buf, int nh) {            // 4 x ds_read_b128
#pragma unroll
        for (int cf = 0; cf < 2; cf++)
#pragma unroll
            for (int ks = 0; ks < 2; ks++)
                bfr[cf][ks] = *(const bf16x8*)(sB[buf] + nh * 16384 + wc * 4096 +
                              (cf * 16 + l16) * 128 + ((((ks << 2) | lg) ^ lx7) << 4));
    };
    auto MMA = [&](int mh, int nh) {              // 16 MFMA, 8 indep chains
        __builtin_amdgcn_s_setprio(1);
#pragma unroll
        for (int rf = 0; rf < 4; rf++)
#pragma unroll
            for (int cf = 0; cf < 2; cf++)
#pragma unroll
                for (int ks = 0; ks < 2; ks++)
                    acc[mh * 4 + rf][nh * 2 + cf] =
                        mfma16(af[rf][ks], bfr[cf][ks], acc[mh * 4 + rf][nh * 2 + cf]);
        __builtin_amdgcn_s_setprio(0);
    };

    const int nk = K >> 6;   // 16
    // prologue: HT g=0..6 = A0(0),B1(0),A1(0),B0(0),A0(1),B1(1),A1(1)
    ST_A(0, 0, 0);  ST_B(0, 1, 0);  ST_A(0, 1, 0);  ST_B(0, 0, 0);
    ST_A(1, 0, 64); ST_B(1, 1, 64); ST_A(1, 1, 64);
    asm volatile("s_waitcnt vmcnt(6)" ::: "memory");   // kt0's 4 HT landed
    __builtin_amdgcn_s_barrier();
    __builtin_amdgcn_sched_barrier(0);

    for (int kt = 0; kt < nk; kt++) {
        const int buf = kt & 1;
        const int k2 = (kt + 2) << 6;
        // ---- P1: quadrant (0,0); stage B0(kt+1) [region last read: P4 of kt-1]
        LD_A(buf, 0); LD_B(buf, 0);
        if (kt < nk - 1) ST_B(buf ^ 1, 0, (kt + 1) << 6);
        asm volatile("s_waitcnt lgkmcnt(8)" ::: "memory");   // 12 ds_reads issued
        __builtin_amdgcn_s_barrier();
        asm volatile("s_waitcnt lgkmcnt(0)" ::: "memory");
        __builtin_amdgcn_sched_barrier(0);
        MMA(0, 0);
        __builtin_amdgcn_s_barrier();
        __builtin_amdgcn_sched_barrier(0);
        // ---- P2: quadrant (0,1); stage A0(kt+2) [A0 last read: P1]
        LD_B(buf, 1);
        if (kt < nk - 2) ST_A(buf, 0, k2);
        __builtin_amdgcn_s_barrier();
        asm volatile("s_waitcnt lgkmcnt(0)" ::: "memory");
        __builtin_amdgcn_sched_barrier(0);
        MMA(0, 1);
        __builtin_amdgcn_s_barrier();
        __builtin_amdgcn_sched_barrier(0);
        // ---- P3: quadrant (1,1); stage B1(kt+2) [B1 last read: P2]
        LD_A(buf, 1);
        if (kt < nk - 2) ST_B(buf, 1, k2);
        __builtin_amdgcn_s_barrier();
        asm volatile("s_waitcnt lgkmcnt(0)" ::: "memory");
        __builtin_amdgcn_sched_barrier(0);
        MMA(1, 1);
        __builtin_amdgcn_s_barrier();
        __builtin_amdgcn_sched_barrier(0);
        // ---- P4: quadrant (1,0); stage A1(kt+2) [A1 last read: P3]; vmcnt
        LD_B(buf, 0);
        if (kt < nk - 2) ST_A(buf, 1, k2);
        __builtin_amdgcn_s_barrier();
        asm volatile("s_waitcnt lgkmcnt(0)" ::: "memory");
        __builtin_amdgcn_sched_barrier(0);
        MMA(1, 0);
        if (kt < nk - 2)       asm volatile("s_waitcnt vmcnt(6)" ::: "memory");
        else if (kt == nk - 2) asm volatile("s_waitcnt vmcnt(0)" ::: "memory");
        __builtin_amdgcn_s_barrier();      // after this, kt+1's 4 HT are visible
        __builtin_amdgcn_sched_barrier(0);
    }

    // epilogue (r3-verified): cols [0,2048) KV split, [2048,3072) Q*0.125*log2e
#pragma unroll
    for (int cf = 0; cf < 4; cf++) {
        const int col = bcol * 256 + wc * 64 + cf * 16 + l16;
        if (col < 2048) {                 // uniform per block (bcol<8)
            const float bv = bias[col];
            const int h = col >> 7, lo = col & 127;
#pragma unroll
            for (int rf = 0; rf < 8; rf++) {
                int row = brow * 256 + wr * 128 + rf * 16 + lg * 4;
                int b = row >> 11, s = row & 2047;
                if (lo < 64) {   // K -> Kb[bh][s][d]
#pragma unroll
                    for (int r = 0; r < 4; r++)
                        Kout[((size_t)(b * 16 + h) * 2048 + s + r) * 64 + lo] =
                            f2bf(acc[rf][cf][r] + bv);
                } else {         // V -> Vt[bh][d][s], 4 s-values packed
                    u16x4 pk;
#pragma unroll
                    for (int r = 0; r < 4; r++) pk[r] = f2bf(acc[rf][cf][r] + bv);
                    *(u16x4*)(Vout + ((size_t)(b * 16 + h) * 64 + (lo - 64)) * 2048 + s) = pk;
                }
            }
        } else {                          // Q region
            const int qc = col - 2048;
            const float bv = bias2[qc];
            const float qs = 0.125f * LOG2E;
#pragma unroll
            for (int rf = 0; rf < 8; rf++) {
                int row = brow * 256 + wr * 128 + rf * 16 + lg * 4;
#pragma unroll
                for (int r = 0; r < 4; r++)
                    Qout[(size_t)(row + r) * 1024 + qc] =
                        f2bf((acc[rf][cf][r] + bv) * qs);
            }
        }
    }
}

// ---- GEMM: C[M,N] = A[M,K] @ Bt[N,K]^T + bias (128^2, verified) ------------
template <int MODE>
__global__ __launch_bounds__(256) void gemm_bt_k(const ushort* __restrict__ A,
                                                 const ushort* __restrict__ Bt,
                                                 const float* __restrict__ bias,
                                                 void* __restrict__ Cout,
                                                 int M, int N, int K) {
    __shared__ __align__(16) char sA[2][8192];
    __shared__ __align__(16) char sB[2][8192];
    const int tid = threadIdx.x;
    const int nbc = N >> 7;
    const int cpx = (gridDim.x >> 3);
    const int swzb = (blockIdx.x & 7) * cpx + (blockIdx.x >> 3);
    const int brow = swzb / nbc, bcol = swzb % nbc;
    const int w = tid >> 6, lane = tid & 63;
    const int wr = w >> 1, wc = w & 1;
    const int lg = lane >> 4, l16 = lane & 15;

    f32x4 acc[4][4] = {};

    const int r0 = tid >> 2;
    const int sl = (tid & 3) ^ (r0 & 3);
    const ushort* a0 = A + (size_t)(brow * 128 + r0) * K + sl * 8;
    const ushort* a1 = A + (size_t)(brow * 128 + 64 + r0) * K + sl * 8;
    const ushort* b0 = Bt + (size_t)(bcol * 128 + r0) * K + sl * 8;
    const ushort* b1 = Bt + (size_t)(bcol * 128 + 64 + r0) * K + sl * 8;

    const int arow = wr * 64 + l16;
    const int bcolr = wc * 64 + l16;

    auto STAGE = [&](int buf, int k0) {
        gload16(a0 + k0, sA[buf] + w * 1024);
        gload16(a1 + k0, sA[buf] + 4096 + w * 1024);
        gload16(b0 + k0, sB[buf] + w * 1024);
        gload16(b1 + k0, sB[buf] + 4096 + w * 1024);
    };

    const int nk = K >> 5;
    STAGE(0, 0);

    for (int k0 = 0; k0 < nk; k0++) {
        const int buf = k0 & 1;
        if (k0 < nk - 1) {
            STAGE(buf ^ 1, (k0 + 1) << 5);
            asm volatile("s_waitcnt vmcnt(4)" ::: "memory");  // tile k0 landed
        } else {
            asm volatile("s_waitcnt vmcnt(0)" ::: "memory");
        }
        __builtin_amdgcn_s_barrier();
        __builtin_amdgcn_sched_barrier(0);

        bf16x8 af[4], bfr[4];
#pragma unroll
        for (int rf = 0; rf < 4; rf++) {
            int rr = arow + rf * 16;
            af[rf] = *(const bf16x8*)(sA[buf] + rr * 64 + ((lg * 16) ^ ((rr & 3) << 4)));
        }
#pragma unroll
        for (int cf = 0; cf < 4; cf++) {
            int rr = bcolr + cf * 16;
            bfr[cf] = *(const bf16x8*)(sB[buf] + rr * 64 + ((lg * 16) ^ ((rr & 3) << 4)));
        }
#pragma unroll
        for (int rf = 0; rf < 4; rf++)
#pragma unroll
            for (int cf = 0; cf < 4; cf++)
                acc[rf][cf] = mfma16(af[rf], bfr[cf], acc[rf][cf]);
        __builtin_amdgcn_s_barrier();     // reads done before buf is re-staged
    }

#pragma unroll
    for (int cf = 0; cf < 4; cf++) {
        const int col = bcol * 128 + wc * 64 + cf * 16 + l16;
        const float bv = bias[col];
#pragma unroll
        for (int rf = 0; rf < 4; rf++) {
            int row = brow * 128 + wr * 64 + rf * 16 + lg * 4;
#pragma unroll
            for (int r = 0; r < 4; r++) {
                float v = acc[rf][cf][r] + bv;
                if (MODE == 1) ((float*)Cout)[(size_t)(row + r) * N + col] = v;
                else           ((ushort*)Cout)[(size_t)(row + r) * N + col] = f2bf(v);
            }
        }
    }
}

// ---- flash attention, swapped operands, fat 64q-per-wave tiles -------------
// (round-1 verified structure: 2 LDS buffers, STAGE(next)->vmcnt(4)->barrier
//  ->compute->barrier)
__global__ __launch_bounds__(256, 2) void attn2_k(const ushort* __restrict__ Qg,
                                                  const ushort* __restrict__ Kg,
                                                  const ushort* __restrict__ Vg,
                                                  ushort* __restrict__ ctx) {
    __shared__ __align__(16) char sK[2][8192];   // [64 kk][64 d], row 128B, XOR-swz
    __shared__ __align__(16) char sV[2][8192];   // [64 d][64 kk], row 128B, XOR-swz
    __shared__ float lx2[256];                   // l exchange (4 q-groups x 64 lanes)
    const int tid = threadIdx.x;
    const int wg = ((blockIdx.x & 7) << 6) | (blockIdx.x >> 3);   // XCD swizzle, 512%8==0
    const int bh = wg >> 4, qt = wg & 15;
    const int b = bh >> 4, h = bh & 15;
    const int w = tid >> 6, lane = tid & 63;
    const int ql = lane & 31, hi = lane >> 5;
    const int ksub = w & 1;          // which 32-kk subtile this wave owns
    const int qq = w >> 1;           // which 64 q-cols this wave pair owns

    const ushort* Kh = Kg + (size_t)bh * (Sc * 64);
    const ushort* Vh = Vg + (size_t)bh * (64 * Sc);

    // Q fragments for two 32-col groups (B-operand: col=q, 8 contig d/lane-half)
    const int qrow0 = qt * 128 + qq * 64 + ql;
    bf16x8 qf[2][4];
#pragma unroll
    for (int qg = 0; qg < 2; qg++) {
        const ushort* qp = Qg + ((size_t)(b * Sc + qrow0 + qg * 32)) * Dc + h * HDc + hi * 8;
#pragma unroll
        for (int jd = 0; jd < 4; jd++) qf[qg][jd] = *(const bf16x8*)(qp + jd * 16);
    }

    // bf16 1.0 x8 for the row-sum MFMA
    const u16x8 ones_u = {0x3F80, 0x3F80, 0x3F80, 0x3F80, 0x3F80, 0x3F80, 0x3F80, 0x3F80};
    const bf16x8 ones8 = __builtin_bit_cast(bf16x8, ones_u);

    // staging: K tile 64x128B + V tile 64x128B; 256 thr x 4 chunks (2K + 2V).
    const int rw = w * 16 + (lane >> 3);
    const int sl = (lane & 7) ^ (lane >> 3);

    f32x16 o[2][2] = {};     // [dg][qg]
    f32x16 ls[2] = {};       // [qg]
    const float MH = 8.0f * LOG2E;
    const int sw = (ql & 7) << 4;                 // read-side XOR swizzle

    auto STAGE = [&](int buf, int kt) {
#pragma unroll
        for (int j = 0; j < 2; j++) {
            gload16(Kh + (size_t)(kt * 64 + rw + 8 * j) * 64 + sl * 8,
                    sK[buf] + w * 2048 + j * 1024);
            gload16(Vh + (size_t)(rw + 8 * j) * Sc + kt * 64 + sl * 8,
                    sV[buf] + w * 2048 + j * 1024);
        }
    };

    int cur = 0;
    STAGE(0, 0);

    constexpr int NT = Sc / 64;
    for (int kt = 0; kt < NT; kt++) {
        if (kt < NT - 1) {
            STAGE(cur ^ 1, kt + 1);
            asm volatile("s_waitcnt vmcnt(4)" ::: "memory");   // tile kt complete
        } else {
            asm volatile("s_waitcnt vmcnt(0)" ::: "memory");
        }
        __builtin_amdgcn_s_barrier();
        __builtin_amdgcn_sched_barrier(0);

        // K fragments once, reused for both q-groups
        bf16x8 kf[4];
        {
            const char* kb = sK[cur] + (ksub * 32 + ql) * 128;
#pragma unroll
            for (int jd = 0; jd < 4; jd++)
                kf[jd] = *(const bf16x8*)(kb + ((jd * 32 + hi * 16) ^ sw));
        }

        // S'[kk-sub][q] = qk*0.125*log2e - 8*log2e via C-init
        f32x16 st[2];
#pragma unroll
        for (int qg = 0; qg < 2; qg++)
#pragma unroll
            for (int i = 0; i < 16; i++) st[qg][i] = -MH;
        __builtin_amdgcn_s_setprio(1);
#pragma unroll
        for (int qg = 0; qg < 2; qg++)
#pragma unroll
            for (int jd = 0; jd < 4; jd++)
                st[qg] = mfma32(kf[jd], qf[qg][jd], st[qg]);
        __builtin_amdgcn_s_setprio(0);

        // p = exp2(st)
#pragma unroll
        for (int qg = 0; qg < 2; qg++)
#pragma unroll
            for (int i = 0; i < 16; i++) st[qg][i] = fexp2(st[qg][i]);

        // P -> B-frags (T12), per q-group
        bf16x8 pf[2][2];
#pragma unroll
        for (int qg = 0; qg < 2; qg++) {
            unsigned a0 = cvtpk(st[qg][0],  st[qg][1]);
            unsigned a1 = cvtpk(st[qg][2],  st[qg][3]);
            unsigned a2 = cvtpk(st[qg][4],  st[qg][5]);
            unsigned a3 = cvtpk(st[qg][6],  st[qg][7]);
            swap32(a0, a2); swap32(a1, a3);
            u32x4 f0v = {a0, a1, a2, a3};
            pf[qg][0] = __builtin_bit_cast(bf16x8, f0v);
            unsigned c0 = cvtpk(st[qg][8],  st[qg][9]);
            unsigned c1 = cvtpk(st[qg][10], st[qg][11]);
            unsigned c2 = cvtpk(st[qg][12], st[qg][13]);
            unsigned c3 = cvtpk(st[qg][14], st[qg][15]);
            swap32(c0, c2); swap32(c1, c3);
            u32x4 f1v = {c0, c1, c2, c3};
            pf[qg][1] = __builtin_bit_cast(bf16x8, f1v);
        }

        // V fragments once, reused across both q-groups
        bf16x8 vf[2][2];   // [dg][ks]
#pragma unroll
        for (int dg = 0; dg < 2; dg++) {
            const char* vb = sV[cur] + (dg * 32 + ql) * 128;
#pragma unroll
            for (int ks = 0; ks < 2; ks++)
                vf[dg][ks] = *(const bf16x8*)(vb + ((ksub * 64 + ks * 32 + hi * 16) ^ sw));
        }

        // PV + ones-MFMA row-sum: 12 MFMAs, 3 indep chains per q-group
        __builtin_amdgcn_s_setprio(1);
#pragma unroll
        for (int qg = 0; qg < 2; qg++)
#pragma unroll
            for (int ks = 0; ks < 2; ks++) {
                o[0][qg] = mfma32(vf[0][ks], pf[qg][ks], o[0][qg]);
                o[1][qg] = mfma32(vf[1][ks], pf[qg][ks], o[1][qg]);
                ls[qg]   = mfma32(ones8,     pf[qg][ks], ls[qg]);
            }
        __builtin_amdgcn_s_setprio(0);

        __builtin_amdgcn_s_barrier();     // protect buffer reuse (no vmem drain)
        cur ^= 1;
    }

    // cross-wave (pair) combine: waves ksub=1 export, ksub=0 reduce + write.
    __syncthreads();                      // full sync before LDS reuse
    float* ox = qq ? (float*)sV : (float*)sK;   // 16 KB per pair (exact fit)
    if (ksub) {
#pragma unroll
        for (int dg = 0; dg < 2; dg++)
#pragma unroll
            for (int qg = 0; qg < 2; qg++)
#pragma unroll
                for (int i = 0; i < 16; i++)
                    ox[((dg * 2 + qg) * 16 + i) * 64 + lane] = o[dg][qg][i];
        lx2[(qq * 2 + 0) * 64 + lane] = ls[0][0];
        lx2[(qq * 2 + 1) * 64 + lane] = ls[1][0];
    }
    __syncthreads();
    if (!ksub) {
#pragma unroll
        for (int dg = 0; dg < 2; dg++)
#pragma unroll
            for (int qg = 0; qg < 2; qg++)
#pragma unroll
                for (int i = 0; i < 16; i++)
                    o[dg][qg][i] += ox[((dg * 2 + qg) * 16 + i) * 64 + lane];
        const float inv0 = 1.0f / (ls[0][0] + lx2[(qq * 2 + 0) * 64 + lane]);
        const float inv1 = 1.0f / (ls[1][0] + lx2[(qq * 2 + 1) * 64 + lane]);
#pragma unroll
        for (int qg = 0; qg < 2; qg++) {
            const float inv = qg ? inv1 : inv0;
            ushort* cp = ctx + ((size_t)(b * Sc + qrow0 + qg * 32)) * Dc + h * HDc;
#pragma unroll
            for (int dg = 0; dg < 2; dg++)
#pragma unroll
                for (int g = 0; g < 4; g++) {
                    u16x4 pk;
#pragma unroll
                    for (int r = 0; r < 4; r++)
                        pk[r] = f2bf(o[dg][qg][g * 4 + r] * inv);
                    *(u16x4*)(cp + dg * 32 + g * 8 + hi * 4) = pk;
                }
        }
    }
}

extern "C" void kernel_launch(void* const* d_in, const int* in_sizes, int n_in,
                              void* d_out, int out_size, void* d_ws, size_t ws_size,
                              hipStream_t stream) {
    const float* emb  = (const float*)d_in[0];
    const float* W_kv = (const float*)d_in[1];
    const float* b_kv = (const float*)d_in[2];
    const float* W_q  = (const float*)d_in[3];
    const float* b_q  = (const float*)d_in[4];
    const float* W_o  = (const float*)d_in[5];
    const float* b_o  = (const float*)d_in[6];
    float* out = (float*)d_out;

    const int BS = Bc * Sc;           // 4096 rows
    ushort* embb  = (ushort*)d_ws;                      // 4096x1024
    ushort* wallt = embb  + (size_t)BS * Dc;            // 4096x1024 (Wkv^T|Wq^T|Wo^T)
    ushort* wot   = wallt + (size_t)3 * Dc * Dc;        // alias: rows 3072..4095
    ushort* Kb    = wallt + (size_t)4 * Dc * Dc;        // 32 x 2048 x 64
    ushort* Vtb   = Kb    + (size_t)32 * Sc * HDc;      // 32 x 64 x 2048
    ushort* Qb    = Vtb   + (size_t)32 * Sc * HDc;      // 4096x1024 (pre-scaled)
    ushort* ctxb  = Qb    + (size_t)BS * Dc;            // 4096x1024
    // total ~48 MB of d_ws

    prep_k<<<6144, 256, 0, stream>>>(emb, embb, W_kv, W_q, W_o, wallt);

    // merged KV+Q projection: 256^2 tiles, 8-phase, grid 16x12 = 192 (%8==0)
    gemm256_kv8_k<<<(BS / 256) * (3072 / 256), 512, 0, stream>>>(
        embb, wallt, b_kv, b_q, Kb, Vtb, Qb, 3072, Dc);

    // fat-wave attn: 128 q-rows per block, grid 512 (%8==0)
    attn2_k<<<Bc * Hc * (Sc / 128), 256, 0, stream>>>(Qb, Kb, Vtb, ctxb);

    // out projection: verified 128^2 kernel, grid 256 (%8==0)
    gemm_bt_k<1><<<(BS / 128) * (Dc / 128), 256, 0, stream>>>(
        ctxb, wot, b_o, out, BS, Dc, Dc);
}

// Round 5
// 113.632 us; speedup vs baseline: 1.0479x; 1.0479x over previous
//
#include <hip/hip_runtime.h>
#include <hip/hip_bf16.h>

// MultiHeadCrossAttention: B=2,S=2048,D=1024,H=16,HD=64
// prep(cvt emb + transpose weights, fused), merged GEMM(KV+Q -> Kb,Vt,Qb*c)
// on the verified 128^2 2-phase kernel (r1, 53us — 256^2 was grid-starved),
// swapped-operand flash-attn with KVBLK=128 (halved iteration count: one
// stage+vmcnt+barrier-pair per 128 kk, two sequential 32-kk sub-phases per
// wave reusing registers), GEMM(out,f32).

typedef unsigned short ushort;
typedef __attribute__((ext_vector_type(4))) float f32x4;
typedef __attribute__((ext_vector_type(16))) float f32x16;
typedef __attribute__((ext_vector_type(8))) __bf16 bf16x8;
typedef __attribute__((ext_vector_type(8))) unsigned short u16x8;
typedef __attribute__((ext_vector_type(4))) unsigned short u16x4;
typedef __attribute__((ext_vector_type(4))) unsigned int u32x4;

#define LOG2E 1.44269504088896340736f

constexpr int Bc = 2, Sc = 2048, Dc = 1024, Hc = 16, HDc = 64;

__device__ inline ushort f2bf(float f) {
    unsigned u = __builtin_bit_cast(unsigned, f);
    u += 0x7fffu + ((u >> 16) & 1u);   // RNE (inputs finite)
    return (ushort)(u >> 16);
}

__device__ inline float fexp2(float x) {
#if __has_builtin(__builtin_amdgcn_exp2f)
    return __builtin_amdgcn_exp2f(x);   // single v_exp_f32, hazard-safe
#else
    return exp2f(x);
#endif
}

__device__ inline void gload16(const void* g, void* l) {
    __builtin_amdgcn_global_load_lds((const __attribute__((address_space(1))) void*)g,
                                     (__attribute__((address_space(3))) void*)l, 16, 0, 0);
}

__device__ inline f32x4 mfma16(bf16x8 a, bf16x8 b, f32x4 c) {
    return __builtin_amdgcn_mfma_f32_16x16x32_bf16(a, b, c, 0, 0, 0);
}
__device__ inline f32x16 mfma32(bf16x8 a, bf16x8 b, f32x16 c) {
    return __builtin_amdgcn_mfma_f32_32x32x16_bf16(a, b, c, 0, 0, 0);
}
__device__ inline unsigned cvtpk(float lo, float hi_) {
    unsigned r; asm("v_cvt_pk_bf16_f32 %0, %1, %2" : "=v"(r) : "v"(lo), "v"(hi_)); return r;
}
__device__ inline void swap32(unsigned& a, unsigned& b) {
    asm("v_permlane32_swap_b32 %0, %1" : "+v"(a), "+v"(b));
}

// ---- fused preprocessing: emb cvt (blocks 0..2047) + 3 weight transposes ---
__global__ __launch_bounds__(256) void prep_k(const float* __restrict__ emb,
                                              ushort* __restrict__ embb,
                                              const float* __restrict__ Wkv,
                                              const float* __restrict__ Wq,
                                              const float* __restrict__ Wo,
                                              ushort* __restrict__ WtAll) {
    const int bid = blockIdx.x;
    if (bid < 2048) {                     // emb f32 -> bf16, 8 elems/thread
        int i = bid * 256 + threadIdx.x;
        const float4* p = (const float4*)emb;
        float4 a = p[2 * i], b = p[2 * i + 1];
        u16x8 r;
        r[0] = f2bf(a.x); r[1] = f2bf(a.y); r[2] = f2bf(a.z); r[3] = f2bf(a.w);
        r[4] = f2bf(b.x); r[5] = f2bf(b.y); r[6] = f2bf(b.z); r[7] = f2bf(b.w);
        ((u16x8*)embb)[i] = r;
        return;
    }
    // transpose W (K=1024 x N) -> WtAll rows [rowofs, rowofs+N) x 1024, bf16
    __shared__ float t[32][33];
    int tb = bid - 2048;
    const float* W; int N, rowofs;
    if (tb < 2048)      { W = Wkv; N = 2048; rowofs = 0; }
    else if (tb < 3072) { W = Wq;  N = 1024; rowofs = 2048; tb -= 2048; }
    else                { W = Wo;  N = 1024; rowofs = 3072; tb -= 3072; }
    const int nbx = N >> 5;
    const int bx = tb % nbx, by = tb / nbx;
    const int tx = threadIdx.x & 31, ty = threadIdx.x >> 5;
    const int bj = bx * 32, bi = by * 32;
#pragma unroll
    for (int i = 0; i < 4; i++) {
        int r = ty + i * 8;
        t[r][tx] = W[(size_t)(bi + r) * N + bj + tx];
    }
    __syncthreads();
#pragma unroll
    for (int i = 0; i < 4; i++) {
        int r = ty + i * 8;
        WtAll[(size_t)(rowofs + bj + r) * 1024 + bi + tx] = f2bf(t[tx][r]);
    }
}

// ---- GEMM: C[M,N] = A[M,K] @ Bt[N,K]^T + bias (128^2, r1-verified) ---------
// 2-phase counted-vmcnt pipeline: STAGE(next) -> vmcnt(4) -> barrier ->
// ds_read+MFMA -> barrier. Prefetch overlaps the whole compute phase.
// MODE 1: f32 C row-major.
// MODE 3: merged KV+Q epilogue. cols [0,2048): KV split -> Kb[bh][s][64],
//   Vt[bh][64][s]; cols [2048,3072): Q*(0.125*log2e) -> Qout row-major.
template <int MODE>
__global__ __launch_bounds__(256) void gemm_bt_k(const ushort* __restrict__ A,
                                                 const ushort* __restrict__ Bt,
                                                 const float* __restrict__ bias,
                                                 const float* __restrict__ bias2,
                                                 void* __restrict__ Cout,
                                                 ushort* __restrict__ Vout,
                                                 ushort* __restrict__ Qout,
                                                 int M, int N, int K) {
    __shared__ __align__(16) char sA[2][8192];
    __shared__ __align__(16) char sB[2][8192];
    const int tid = threadIdx.x;
    const int nbc = N >> 7;
    // bijective XCD swizzle (grid % 8 == 0 for all call sites)
    const int cpx = (gridDim.x >> 3);
    const int swzb = (blockIdx.x & 7) * cpx + (blockIdx.x >> 3);
    const int brow = swzb / nbc, bcol = swzb % nbc;
    const int w = tid >> 6, lane = tid & 63;
    const int wr = w >> 1, wc = w & 1;
    const int lg = lane >> 4, l16 = lane & 15;

    f32x4 acc[4][4] = {};

    const int r0 = tid >> 2;
    const int sl = (tid & 3) ^ (r0 & 3);
    const ushort* a0 = A + (size_t)(brow * 128 + r0) * K + sl * 8;
    const ushort* a1 = A + (size_t)(brow * 128 + 64 + r0) * K + sl * 8;
    const ushort* b0 = Bt + (size_t)(bcol * 128 + r0) * K + sl * 8;
    const ushort* b1 = Bt + (size_t)(bcol * 128 + 64 + r0) * K + sl * 8;

    const int arow = wr * 64 + l16;
    const int bcolr = wc * 64 + l16;

    auto STAGE = [&](int buf, int k0) {
        gload16(a0 + k0, sA[buf] + w * 1024);
        gload16(a1 + k0, sA[buf] + 4096 + w * 1024);
        gload16(b0 + k0, sB[buf] + w * 1024);
        gload16(b1 + k0, sB[buf] + 4096 + w * 1024);
    };

    const int nk = K >> 5;
    STAGE(0, 0);

    for (int k0 = 0; k0 < nk; k0++) {
        const int buf = k0 & 1;
        if (k0 < nk - 1) {
            STAGE(buf ^ 1, (k0 + 1) << 5);
            asm volatile("s_waitcnt vmcnt(4)" ::: "memory");  // tile k0 landed
        } else {
            asm volatile("s_waitcnt vmcnt(0)" ::: "memory");
        }
        __builtin_amdgcn_s_barrier();
        __builtin_amdgcn_sched_barrier(0);

        bf16x8 af[4], bfr[4];
#pragma unroll
        for (int rf = 0; rf < 4; rf++) {
            int rr = arow + rf * 16;
            af[rf] = *(const bf16x8*)(sA[buf] + rr * 64 + ((lg * 16) ^ ((rr & 3) << 4)));
        }
#pragma unroll
        for (int cf = 0; cf < 4; cf++) {
            int rr = bcolr + cf * 16;
            bfr[cf] = *(const bf16x8*)(sB[buf] + rr * 64 + ((lg * 16) ^ ((rr & 3) << 4)));
        }
#pragma unroll
        for (int rf = 0; rf < 4; rf++)
#pragma unroll
            for (int cf = 0; cf < 4; cf++)
                acc[rf][cf] = mfma16(af[rf], bfr[cf], acc[rf][cf]);
        __builtin_amdgcn_s_barrier();     // reads done before buf is re-staged
    }

#pragma unroll
    for (int cf = 0; cf < 4; cf++) {
        const int col = bcol * 128 + wc * 64 + cf * 16 + l16;
        if constexpr (MODE == 3) {
            if (col < 2048) {          // KV region (uniform per block: bcol<16)
                const float bv = bias[col];
                const int h = col >> 7, lo = col & 127;
#pragma unroll
                for (int rf = 0; rf < 4; rf++) {
                    int row = brow * 128 + wr * 64 + rf * 16 + lg * 4;
                    int b = row >> 11, s = row & 2047;
                    if (lo < 64) {   // K -> Kb[bh][s][d]
                        ushort* Kout = (ushort*)Cout;
#pragma unroll
                        for (int r = 0; r < 4; r++)
                            Kout[((size_t)(b * 16 + h) * 2048 + s + r) * 64 + lo] =
                                f2bf(acc[rf][cf][r] + bv);
                    } else {         // V -> Vt[bh][d][s], 4 s-values packed
                        u16x4 pk;
#pragma unroll
                        for (int r = 0; r < 4; r++) pk[r] = f2bf(acc[rf][cf][r] + bv);
                        *(u16x4*)(Vout + ((size_t)(b * 16 + h) * 64 + (lo - 64)) * 2048 + s) = pk;
                    }
                }
            } else {                   // Q region: scale by 0.125*log2e (exp2 fold)
                const int qc = col - 2048;
                const float bv = bias2[qc];
                const float qs = 0.125f * LOG2E;
#pragma unroll
                for (int rf = 0; rf < 4; rf++) {
                    int row = brow * 128 + wr * 64 + rf * 16 + lg * 4;
#pragma unroll
                    for (int r = 0; r < 4; r++)
                        Qout[(size_t)(row + r) * 1024 + qc] =
                            f2bf((acc[rf][cf][r] + bv) * qs);
                }
            }
        } else {
            const float bv = bias[col];
#pragma unroll
            for (int rf = 0; rf < 4; rf++) {
                int row = brow * 128 + wr * 64 + rf * 16 + lg * 4;
#pragma unroll
                for (int r = 0; r < 4; r++) {
                    float v = acc[rf][cf][r] + bv;
                    if (MODE == 1) ((float*)Cout)[(size_t)(row + r) * N + col] = v;
                    else           ((ushort*)Cout)[(size_t)(row + r) * N + col] = f2bf(v);
                }
            }
        }
    }
}

// ---- flash attention, swapped operands, KVBLK=128 --------------------------
// Grid 512 = 32 bh x 16 qtiles(128). 4 waves: pair (w>>1) owns 64 q-cols,
// member (w&1) owns kk chunks {ksub*32+kh*64} per tile. K/V LDS fragments
// reused 2x across q-groups. Q pre-scaled by 0.125*log2e; QK acc init
// = -8*log2e so p = exp2(st). Row-sum l via ones-MFMA.
// r5: 128-kk tiles -> 16 iterations (was 32): ONE stage + counted vmcnt(8)
// + barrier-pair per 128 kk; two sequential 32-kk sub-phases (kh) per wave
// reuse st/pf/kf/vf registers (VGPR flat). Sync structure byte-identical to
// the r1-verified 2-buffer loop. LDS 65KB -> 2 blk/CU (unchanged).
__global__ __launch_bounds__(256, 2) void attn3_k(const ushort* __restrict__ Qg,
                                                  const ushort* __restrict__ Kg,
                                                  const ushort* __restrict__ Vg,
                                                  ushort* __restrict__ ctx) {
    __shared__ __align__(16) char sK[2][16384];  // [128 kk][64 d], 128B rows, XOR-swz
    __shared__ __align__(16) char sV[2][16384];  // [2 kh][64 d][64 kk], 128B rows, XOR-swz
    __shared__ float lx2[256];                   // l exchange (4 q-groups x 64 lanes)
    const int tid = threadIdx.x;
    const int wg = ((blockIdx.x & 7) << 6) | (blockIdx.x >> 3);   // XCD swizzle, 512%8==0
    const int bh = wg >> 4, qt = wg & 15;
    const int b = bh >> 4, h = bh & 15;
    const int w = tid >> 6, lane = tid & 63;
    const int ql = lane & 31, hi = lane >> 5;
    const int ksub = w & 1;          // which 32-kk subchunk (per kh) this wave owns
    const int qq = w >> 1;           // which 64 q-cols this wave pair owns

    const ushort* Kh = Kg + (size_t)bh * (Sc * 64);
    const ushort* Vh = Vg + (size_t)bh * (64 * Sc);

    // Q fragments for two 32-col groups (B-operand: col=q, 8 contig d/lane-half)
    const int qrow0 = qt * 128 + qq * 64 + ql;
    bf16x8 qf[2][4];
#pragma unroll
    for (int qg = 0; qg < 2; qg++) {
        const ushort* qp = Qg + ((size_t)(b * Sc + qrow0 + qg * 32)) * Dc + h * HDc + hi * 8;
#pragma unroll
        for (int jd = 0; jd < 4; jd++) qf[qg][jd] = *(const bf16x8*)(qp + jd * 16);
    }

    // bf16 1.0 x8 for the row-sum MFMA
    const u16x8 ones_u = {0x3F80, 0x3F80, 0x3F80, 0x3F80, 0x3F80, 0x3F80, 0x3F80, 0x3F80};
    const bf16x8 ones8 = __builtin_bit_cast(bf16x8, ones_u);

    // staging: K 128x128B (16KB) + V 2x 64x128B subtiles (16KB); 256 thr x
    // 8 chunks (4K + 4V). LDS slot (row, c) holds global chunk c^(row&7);
    // linear gload_lds dest, pre-swizzled global source (m173).
    const int l8 = lane >> 3;                    // row&7 of every staged row
    const int sl = (lane & 7) ^ l8;              // pre-swizzled chunk

    f32x16 o[2][2] = {};     // [dg][qg]
    f32x16 ls[2] = {};       // [qg]
    const float MH = 8.0f * LOG2E;
    const int sw = (ql & 7) << 4;                // read-side XOR swizzle

    auto STAGE = [&](int buf, int kt) {
#pragma unroll
        for (int j = 0; j < 4; j++) {
            // K rows w*32 + j*8 + l8  (covers 0..127 over 4 waves)
            gload16(Kh + (size_t)(kt * 128 + w * 32 + j * 8 + l8) * 64 + sl * 8,
                    sK[buf] + w * 4096 + j * 1024);
            // V subtile (w>>1) [kk kh*64..+64), rows (w&1)*32 + j*8 + l8
            gload16(Vh + (size_t)((w & 1) * 32 + j * 8 + l8) * Sc +
                        kt * 128 + (w >> 1) * 64 + sl * 8,
                    sV[buf] + (w >> 1) * 8192 + (w & 1) * 4096 + j * 1024);
        }
    };

    int cur = 0;
    STAGE(0, 0);

    constexpr int NT = Sc / 128;     // 16
    for (int kt = 0; kt < NT; kt++) {
        if (kt < NT - 1) {
            STAGE(cur ^ 1, kt + 1);
            asm volatile("s_waitcnt vmcnt(8)" ::: "memory");   // tile kt complete
        } else {
            asm volatile("s_waitcnt vmcnt(0)" ::: "memory");
        }
        __builtin_amdgcn_s_barrier();
        __builtin_amdgcn_sched_barrier(0);

#pragma unroll
        for (int kh = 0; kh < 2; kh++) {
            // K fragments once per sub-phase, reused for both q-groups
            bf16x8 kf[4];
            {
                const char* kb = sK[cur] + (kh * 64 + ksub * 32 + ql) * 128;
#pragma unroll
                for (int jd = 0; jd < 4; jd++)
                    kf[jd] = *(const bf16x8*)(kb + ((jd * 32 + hi * 16) ^ sw));
            }

            // S'[kk-sub][q] = qk*0.125*log2e - 8*log2e via C-init
            f32x16 st[2];
#pragma unroll
            for (int qg = 0; qg < 2; qg++)
#pragma unroll
                for (int i = 0; i < 16; i++) st[qg][i] = -MH;
            __builtin_amdgcn_s_setprio(1);
#pragma unroll
            for (int qg = 0; qg < 2; qg++)
#pragma unroll
                for (int jd = 0; jd < 4; jd++)
                    st[qg] = mfma32(kf[jd], qf[qg][jd], st[qg]);
            __builtin_amdgcn_s_setprio(0);

            // p = exp2(st)
#pragma unroll
            for (int qg = 0; qg < 2; qg++)
#pragma unroll
                for (int i = 0; i < 16; i++) st[qg][i] = fexp2(st[qg][i]);

            // P -> B-frags (T12), per q-group
            bf16x8 pf[2][2];
#pragma unroll
            for (int qg = 0; qg < 2; qg++) {
                unsigned a0 = cvtpk(st[qg][0],  st[qg][1]);
                unsigned a1 = cvtpk(st[qg][2],  st[qg][3]);
                unsigned a2 = cvtpk(st[qg][4],  st[qg][5]);
                unsigned a3 = cvtpk(st[qg][6],  st[qg][7]);
                swap32(a0, a2); swap32(a1, a3);
                u32x4 f0v = {a0, a1, a2, a3};
                pf[qg][0] = __builtin_bit_cast(bf16x8, f0v);
                unsigned c0 = cvtpk(st[qg][8],  st[qg][9]);
                unsigned c1 = cvtpk(st[qg][10], st[qg][11]);
                unsigned c2 = cvtpk(st[qg][12], st[qg][13]);
                unsigned c3 = cvtpk(st[qg][14], st[qg][15]);
                swap32(c0, c2); swap32(c1, c3);
                u32x4 f1v = {c0, c1, c2, c3};
                pf[qg][1] = __builtin_bit_cast(bf16x8, f1v);
            }

            // V fragments once per sub-phase, reused across both q-groups
            bf16x8 vf[2][2];   // [dg][ks]
#pragma unroll
            for (int dg = 0; dg < 2; dg++) {
                const char* vb = sV[cur] + kh * 8192 + (dg * 32 + ql) * 128;
#pragma unroll
                for (int ks = 0; ks < 2; ks++)
                    vf[dg][ks] = *(const bf16x8*)(vb + ((ksub * 64 + ks * 32 + hi * 16) ^ sw));
            }

            // PV + ones-MFMA row-sum: 12 MFMAs, 3 indep chains per q-group
            __builtin_amdgcn_s_setprio(1);
#pragma unroll
            for (int qg = 0; qg < 2; qg++)
#pragma unroll
                for (int ks = 0; ks < 2; ks++) {
                    o[0][qg] = mfma32(vf[0][ks], pf[qg][ks], o[0][qg]);
                    o[1][qg] = mfma32(vf[1][ks], pf[qg][ks], o[1][qg]);
                    ls[qg]   = mfma32(ones8,     pf[qg][ks], ls[qg]);
                }
            __builtin_amdgcn_s_setprio(0);
        }

        __builtin_amdgcn_s_barrier();     // protect buffer reuse (no vmem drain)
        cur ^= 1;
    }

    // cross-wave (pair) combine: waves ksub=1 export, ksub=0 reduce + write.
    __syncthreads();                      // full sync before LDS reuse
    float* ox = qq ? (float*)sV : (float*)sK;   // 16 KB per pair
    if (ksub) {
#pragma unroll
        for (int dg = 0; dg < 2; dg++)
#pragma unroll
            for (int qg = 0; qg < 2; qg++)
#pragma unroll
                for (int i = 0; i < 16; i++)
                    ox[((dg * 2 + qg) * 16 + i) * 64 + lane] = o[dg][qg][i];
        lx2[(qq * 2 + 0) * 64 + lane] = ls[0][0];
        lx2[(qq * 2 + 1) * 64 + lane] = ls[1][0];
    }
    __syncthreads();
    if (!ksub) {
#pragma unroll
        for (int dg = 0; dg < 2; dg++)
#pragma unroll
            for (int qg = 0; qg < 2; qg++)
#pragma unroll
                for (int i = 0; i < 16; i++)
                    o[dg][qg][i] += ox[((dg * 2 + qg) * 16 + i) * 64 + lane];
        const float inv0 = 1.0f / (ls[0][0] + lx2[(qq * 2 + 0) * 64 + lane]);
        const float inv1 = 1.0f / (ls[1][0] + lx2[(qq * 2 + 1) * 64 + lane]);
#pragma unroll
        for (int qg = 0; qg < 2; qg++) {
            const float inv = qg ? inv1 : inv0;
            ushort* cp = ctx + ((size_t)(b * Sc + qrow0 + qg * 32)) * Dc + h * HDc;
#pragma unroll
            for (int dg = 0; dg < 2; dg++)
#pragma unroll
                for (int g = 0; g < 4; g++) {
                    u16x4 pk;
#pragma unroll
                    for (int r = 0; r < 4; r++)
                        pk[r] = f2bf(o[dg][qg][g * 4 + r] * inv);
                    *(u16x4*)(cp + dg * 32 + g * 8 + hi * 4) = pk;
                }
        }
    }
}

extern "C" void kernel_launch(void* const* d_in, const int* in_sizes, int n_in,
                              void* d_out, int out_size, void* d_ws, size_t ws_size,
                              hipStream_t stream) {
    const float* emb  = (const float*)d_in[0];
    const float* W_kv = (const float*)d_in[1];
    const float* b_kv = (const float*)d_in[2];
    const float* W_q  = (const float*)d_in[3];
    const float* b_q  = (const float*)d_in[4];
    const float* W_o  = (const float*)d_in[5];
    const float* b_o  = (const float*)d_in[6];
    float* out = (float*)d_out;

    const int BS = Bc * Sc;           // 4096 rows
    ushort* embb  = (ushort*)d_ws;                      // 4096x1024
    ushort* wallt = embb  + (size_t)BS * Dc;            // 4096x1024 (Wkv^T|Wq^T|Wo^T)
    ushort* wot   = wallt + (size_t)3 * Dc * Dc;        // alias: rows 3072..4095
    ushort* Kb    = wallt + (size_t)4 * Dc * Dc;        // 32 x 2048 x 64
    ushort* Vtb   = Kb    + (size_t)32 * Sc * HDc;      // 32 x 64 x 2048
    ushort* Qb    = Vtb   + (size_t)32 * Sc * HDc;      // 4096x1024 (pre-scaled)
    ushort* ctxb  = Qb    + (size_t)BS * Dc;            // 4096x1024
    // total ~48 MB of d_ws

    prep_k<<<6144, 256, 0, stream>>>(emb, embb, W_kv, W_q, W_o, wallt);

    // merged KV+Q projection: 128^2 tiles, N = 3072, grid 768 (%8==0)
    gemm_bt_k<3><<<(BS / 128) * (3072 / 128), 256, 0, stream>>>(
        embb, wallt, b_kv, b_q, Kb, Vtb, Qb, BS, 3072, Dc);

    // KVBLK=128 attn: 128 q-rows per block, grid 512 (%8==0)
    attn3_k<<<Bc * Hc * (Sc / 128), 256, 0, stream>>>(Qb, Kb, Vtb, ctxb);

    // out projection: 128^2, grid 256 (%8==0)
    gemm_bt_k<1><<<(BS / 128) * (Dc / 128), 256, 0, stream>>>(
        ctxb, wot, b_o, nullptr, out, nullptr, nullptr, BS, Dc, Dc);
}